// Round 1
// baseline (904.895 us; speedup 1.0000x reference)
//
#include <hip/hip_runtime.h>
#include <hip/hip_bf16.h>
#include <stdint.h>

#define B_    2048
#define F_    12800
#define DLLM_ 768
#define DFF_  256
#define E_    8
#define GIN_K (DLLM_ + F_)   // 13568 virtual K (cycle column handled as rank-1)
#define KCHUNK 1696          // GIN_K / 8 splits
#define KSPLIT 4
#define KPER  (F_ / KSPLIT)  // 3200

typedef __bf16 bf16x8 __attribute__((ext_vector_type(8)));
typedef float  f32x4  __attribute__((ext_vector_type(4)));

__device__ __forceinline__ unsigned short f2bf(float f) {
    unsigned int u = __float_as_uint(f);
    u += 0x7fffu + ((u >> 16) & 1u);           // RNE (inputs are normal floats)
    return (unsigned short)(u >> 16);
}

// ---------------- fp32 -> bf16 flat convert (xf) ----------------
__global__ __launch_bounds__(256) void k_convert(const float* __restrict__ src,
                                                 unsigned short* __restrict__ dst, int n4) {
    int i = blockIdx.x * 256 + threadIdx.x;
    if (i >= n4) return;
    float4 v = ((const float4*)src)[i];
    ushort4 o;
    o.x = f2bf(v.x); o.y = f2bf(v.y); o.z = f2bf(v.z); o.w = f2bf(v.w);
    ((ushort4*)dst)[i] = o;
}

// ------------- transpose+convert We [e][K][128] -> WeT [e][128][K], Wgen likewise -------------
__global__ __launch_bounds__(256) void k_transpose_bf16(const float* __restrict__ We,
                                                        const float* __restrict__ Wgen,
                                                        unsigned short* __restrict__ WeT,
                                                        unsigned short* __restrict__ WgenT) {
    __shared__ float t[32][33];
    int z = blockIdx.z;
    const float* src = (z < 8) ? (We + (size_t)z * F_ * 128) : Wgen;
    unsigned short* dst = (z < 8) ? (WeT + (size_t)z * 128 * F_) : WgenT;
    int k0 = blockIdx.x * 32, n0 = blockIdx.y * 32;
    int tx = threadIdx.x, ty = threadIdx.y;  // 32 x 8
#pragma unroll
    for (int i = 0; i < 4; i++) {
        int k = k0 + ty + i * 8;
        t[ty + i * 8][tx] = src[(size_t)k * 128 + n0 + tx];
    }
    __syncthreads();
#pragma unroll
    for (int i = 0; i < 4; i++) {
        int n = n0 + ty + i * 8;
        dst[(size_t)n * F_ + k0 + tx] = f2bf(t[tx][ty + i * 8]);
    }
}

// ---------------- gate layer-1: h_pre += A @ Wg1 (fp32, split-K atomics) ----------------
__global__ __launch_bounds__(256) void k_gate1(const float* __restrict__ dkp,
                                               const float* __restrict__ xf,
                                               const float* __restrict__ Wg1,
                                               float* __restrict__ h_pre) {
    __shared__ float As[16][132];  // [k][m], padded
    __shared__ float Bs[16][132];  // [k][n], padded
    int m0 = blockIdx.x * 128;
    int n0 = blockIdx.y * 128;
    int kbeg = blockIdx.z * KCHUNK, kend = kbeg + KCHUNK;
    int t = threadIdx.x;
    int tx = t & 15, ty = t >> 4;

    float acc[8][8];
#pragma unroll
    for (int i = 0; i < 8; i++)
#pragma unroll
        for (int j = 0; j < 8; j++) acc[i][j] = 0.f;

    int lm = t >> 2;           // 0..63
    int lkq = (t & 3) * 4;     // 0,4,8,12
    int br = t >> 5;           // 0..7
    int bc = (t & 31) * 4;     // 0..124

    float4 aReg[2], bReg[2];
    auto preload = [&](int k) {
        const float* Ab; int astr, aoff, wr0;
        if (k < DLLM_) { Ab = dkp; astr = DLLM_; aoff = k; wr0 = k; }
        else           { Ab = xf;  astr = F_;    aoff = k - DLLM_; wr0 = k + 1; }
#pragma unroll
        for (int p = 0; p < 2; p++)
            aReg[p] = *(const float4*)&Ab[(size_t)(m0 + p * 64 + lm) * astr + aoff + lkq];
#pragma unroll
        for (int p = 0; p < 2; p++)
            bReg[p] = *(const float4*)&Wg1[(size_t)(wr0 + p * 8 + br) * 256 + n0 + bc];
    };
    preload(kbeg);
    for (int k = kbeg; k < kend; k += 16) {
        __syncthreads();
#pragma unroll
        for (int p = 0; p < 2; p++) {
            As[lkq + 0][p * 64 + lm] = aReg[p].x;
            As[lkq + 1][p * 64 + lm] = aReg[p].y;
            As[lkq + 2][p * 64 + lm] = aReg[p].z;
            As[lkq + 3][p * 64 + lm] = aReg[p].w;
            *(float4*)&Bs[p * 8 + br][bc] = bReg[p];
        }
        __syncthreads();
        if (k + 16 < kend) preload(k + 16);
#pragma unroll
        for (int kk = 0; kk < 16; kk++) {
            float4 a0 = *(const float4*)&As[kk][ty * 4];
            float4 a1 = *(const float4*)&As[kk][64 + ty * 4];
            float4 b0 = *(const float4*)&Bs[kk][tx * 4];
            float4 b1 = *(const float4*)&Bs[kk][64 + tx * 4];
            float av[8] = {a0.x, a0.y, a0.z, a0.w, a1.x, a1.y, a1.z, a1.w};
            float bv[8] = {b0.x, b0.y, b0.z, b0.w, b1.x, b1.y, b1.z, b1.w};
#pragma unroll
            for (int i = 0; i < 8; i++)
#pragma unroll
                for (int j = 0; j < 8; j++) acc[i][j] = fmaf(av[i], bv[j], acc[i][j]);
        }
    }
#pragma unroll
    for (int i = 0; i < 8; i++) {
        int row = m0 + ((i < 4) ? (ty * 4 + i) : (64 + ty * 4 + i - 4));
#pragma unroll
        for (int j = 0; j < 8; j++) {
            int col = n0 + ((j < 4) ? (tx * 4 + j) : (64 + tx * 4 + j - 4));
            atomicAdd(&h_pre[(size_t)row * 256 + col], acc[i][j]);
        }
    }
}

// ---------------- gate layer-2: gelu, logits, top-2, gates, expert row lists ----------------
__global__ __launch_bounds__(256) void k_gate2(const float* __restrict__ h_pre,
                                               const float* __restrict__ cyc,
                                               const float* __restrict__ Wg1,
                                               const float* __restrict__ bg1,
                                               const float* __restrict__ Wg2,
                                               const float* __restrict__ bg2,
                                               float* __restrict__ gates,
                                               unsigned int* __restrict__ cnt,
                                               unsigned int* __restrict__ rows) {
    __shared__ float hs[32 * 257];
    __shared__ float w2s[256 * 8];
    __shared__ float ls[32][9];
    int r0 = blockIdx.x * 32;
    int t = threadIdx.x;
    const float* w768 = Wg1 + (size_t)DLLM_ * 256;
#pragma unroll 4
    for (int i = 0; i < 32; i++) {
        int c = t;
        float x = h_pre[(size_t)(r0 + i) * 256 + c] + cyc[r0 + i] * w768[c] + bg1[c];
        float x3 = x * x * x;
        float g = 0.5f * x * (1.f + tanhf(0.7978845608028654f * (x + 0.044715f * x3)));
        hs[i * 257 + c] = g;
    }
#pragma unroll
    for (int i = 0; i < 8; i++) w2s[i * 256 + t] = Wg2[i * 256 + t];
    __syncthreads();
    {
        int r = t >> 3, e = t & 7;
        float s = bg2[e];
        for (int k2 = 0; k2 < 256; k2++) s = fmaf(hs[r * 257 + k2], w2s[k2 * 8 + e], s);
        ls[r][e] = s;
    }
    __syncthreads();
    if (t < 32) {
        float l[8];
#pragma unroll
        for (int e = 0; e < 8; e++) l[e] = ls[t][e];
        int i1 = 0; float v1 = l[0];
#pragma unroll
        for (int e = 1; e < 8; e++) if (l[e] > v1) { v1 = l[e]; i1 = e; }
        int i2 = -1; float v2 = -3.0e38f;
#pragma unroll
        for (int e = 0; e < 8; e++) if (e != i1 && l[e] > v2) { v2 = l[e]; i2 = e; }
        float p[8], ps = 0.f;
#pragma unroll
        for (int e = 0; e < 8; e++) { p[e] = expf(l[e] - v1); ps += p[e]; }
        float msum = (p[i1] + p[i2]) / ps;
        float gi = 1.f / (msum + 1e-9f);
        int row = r0 + t;
#pragma unroll
        for (int e = 0; e < 8; e++) {
            float ge = (e == i1 || e == i2) ? (p[e] / ps) * gi : 0.f;
            gates[row * 8 + e] = ge;
        }
        unsigned int s1 = atomicAdd(&cnt[i1], 1u); rows[i1 * 2048 + s1] = (unsigned int)row;
        unsigned int s2 = atomicAdd(&cnt[i2], 1u); rows[i2 * 2048 + s2] = (unsigned int)row;
    }
}

// ---------------- grouped expert GEMM + general GEMM (bf16 MFMA 16x16x32) ----------------
__global__ __launch_bounds__(256) void k_moe(const unsigned short* __restrict__ xfb,
                                             const unsigned short* __restrict__ WeT,
                                             const unsigned short* __restrict__ WgenT,
                                             const float* __restrict__ be,
                                             const float* __restrict__ gates,
                                             const unsigned int* __restrict__ cnt,
                                             const unsigned int* __restrict__ rows,
                                             float* __restrict__ comb,
                                             float* __restrict__ gen) {
    __shared__ unsigned short As[4 * 64 * 8];    // [g][m][8]
    __shared__ unsigned short Bs[4 * 128 * 8];   // [g][n][8]
    __shared__ unsigned int rowid_s[64];
    int e = blockIdx.y, tile = blockIdx.x, split = blockIdx.z;
    int n_rows = (e < 8) ? (int)cnt[e] : 2048;
    if (tile * 64 >= n_rows) return;
    int t = threadIdx.x;
    if (t < 64) {
        int m = tile * 64 + t;
        unsigned int row = (e < 8) ? ((m < n_rows) ? rows[e * 2048 + m] : rows[e * 2048])
                                   : (unsigned int)m;
        rowid_s[t] = row;
    }
    __syncthreads();
    const unsigned short* WT = (e < 8) ? (WeT + (size_t)e * 128 * F_) : WgenT;

    int ag = t >> 6, am = t & 63;
    int bn = t & 127, bg0 = t >> 7;   // 0..1
    int k0 = split * KPER;
    const unsigned short* aptr  = xfb + (size_t)rowid_s[am] * F_ + k0 + ag * 8;
    const unsigned short* bptr0 = WT + (size_t)bn * F_ + k0 + bg0 * 8;
    const unsigned short* bptr1 = WT + (size_t)bn * F_ + k0 + (bg0 + 2) * 8;
    uint4* AsW  = (uint4*)&As[t * 8];
    uint4* BsW0 = (uint4*)&Bs[t * 8];
    uint4* BsW1 = (uint4*)&Bs[(t + 256) * 8];

    int lane = t & 63;
    int lm = lane & 15, lg = lane >> 4;
    int wave = t >> 6, wr = wave >> 1, wc = wave & 1;  // 2x2 wave grid, each 32x64

    f32x4 acc[2][4];
#pragma unroll
    for (int i = 0; i < 2; i++)
#pragma unroll
        for (int j = 0; j < 4; j++) acc[i][j] = (f32x4){0.f, 0.f, 0.f, 0.f};

    uint4 ra = *(const uint4*)aptr;
    uint4 rb0 = *(const uint4*)bptr0;
    uint4 rb1 = *(const uint4*)bptr1;
    for (int kk = 0; kk < KPER; kk += 32) {
        __syncthreads();
        *AsW = ra; *BsW0 = rb0; *BsW1 = rb1;
        __syncthreads();
        if (kk + 32 < KPER) {
            aptr += 32; bptr0 += 32; bptr1 += 32;
            ra = *(const uint4*)aptr; rb0 = *(const uint4*)bptr0; rb1 = *(const uint4*)bptr1;
        }
        bf16x8 af[2], bf[4];
#pragma unroll
        for (int mt = 0; mt < 2; mt++)
            af[mt] = *(const bf16x8*)&As[((lg * 64) + wr * 32 + mt * 16 + lm) * 8];
#pragma unroll
        for (int nt = 0; nt < 4; nt++)
            bf[nt] = *(const bf16x8*)&Bs[((lg * 128) + wc * 64 + nt * 16 + lm) * 8];
#pragma unroll
        for (int mt = 0; mt < 2; mt++)
#pragma unroll
            for (int nt = 0; nt < 4; nt++)
                acc[mt][nt] = __builtin_amdgcn_mfma_f32_16x16x32_bf16(af[mt], bf[nt], acc[mt][nt], 0, 0, 0);
    }
#pragma unroll
    for (int mt = 0; mt < 2; mt++) {
        int rl0 = wr * 32 + mt * 16 + (lane >> 4) * 4;
#pragma unroll
        for (int nt = 0; nt < 4; nt++) {
            int col = wc * 64 + nt * 16 + (lane & 15);
#pragma unroll
            for (int r = 0; r < 4; r++) {
                int rloc = rl0 + r;
                float v = acc[mt][nt][r];
                if (e < 8) {
                    if (tile * 64 + rloc < n_rows) {
                        unsigned int grow = rowid_s[rloc];
                        float g = gates[grow * 8 + e];
                        float bias = (split == 0) ? be[e * 128 + col] : 0.f;
                        atomicAdd(&comb[(size_t)grow * 128 + col], g * (v + bias));
                    }
                } else {
                    atomicAdd(&gen[(size_t)(tile * 64 + rloc) * 128 + col], v);
                }
            }
        }
    }
}

// ---------------- finalize: out = gen + bgen + f32(bf16(comb)) ----------------
__global__ __launch_bounds__(256) void k_final(const float* __restrict__ gen,
                                               const float* __restrict__ comb,
                                               const float* __restrict__ bgen,
                                               float* __restrict__ out) {
    int i = blockIdx.x * 256 + threadIdx.x;
    float g = gen[i] + bgen[i & 127];
    unsigned short cb = f2bf(comb[i]);
    float c = __uint_as_float(((unsigned int)cb) << 16);
    out[i] = g + c;
}

extern "C" void kernel_launch(void* const* d_in, const int* in_sizes, int n_in,
                              void* d_out, int out_size, void* d_ws, size_t ws_size,
                              hipStream_t stream) {
    (void)in_sizes; (void)n_in; (void)out_size; (void)ws_size;
    const float* ccd  = (const float*)d_in[0];
    const float* cyc  = (const float*)d_in[1];
    const float* dkp  = (const float*)d_in[2];
    const float* Wg1  = (const float*)d_in[3];
    const float* bg1  = (const float*)d_in[4];
    const float* Wg2  = (const float*)d_in[5];
    const float* bg2  = (const float*)d_in[6];
    const float* We   = (const float*)d_in[7];
    const float* be   = (const float*)d_in[8];
    const float* Wgen = (const float*)d_in[9];
    const float* bgen = (const float*)d_in[10];
    float* out = (float*)d_out;

    char* ws = (char*)d_ws;
    size_t o = 0;
    unsigned short* xfb   = (unsigned short*)(ws + o); o += (size_t)B_ * F_ * 2;        // 52.4 MB
    unsigned short* WeT   = (unsigned short*)(ws + o); o += (size_t)E_ * 128 * F_ * 2;  // 26.2 MB
    unsigned short* WgenT = (unsigned short*)(ws + o); o += (size_t)128 * F_ * 2;       // 3.3 MB
    float* h_pre = (float*)(ws + o); o += (size_t)B_ * 256 * 4;                          // 2.1 MB
    float* gates = (float*)(ws + o); o += (size_t)B_ * 8 * 4;
    unsigned int* cnt = (unsigned int*)(ws + o); o += 256;
    unsigned int* rows = (unsigned int*)(ws + o); o += (size_t)8 * 2048 * 4;
    float* comb = (float*)(ws + o); o += (size_t)B_ * 128 * 4;
    float* gen  = (float*)(ws + o); o += (size_t)B_ * 128 * 4;

    hipMemsetAsync(h_pre, 0, (size_t)B_ * 256 * 4, stream);
    hipMemsetAsync(comb, 0, (size_t)B_ * 128 * 4, stream);
    hipMemsetAsync(gen,  0, (size_t)B_ * 128 * 4, stream);
    hipMemsetAsync(cnt,  0, 32, stream);

    k_convert<<<(B_ * F_ / 4) / 256, 256, 0, stream>>>(ccd, xfb, B_ * F_ / 4);
    k_transpose_bf16<<<dim3(F_ / 32, 4, 9), dim3(32, 8, 1), 0, stream>>>(We, Wgen, WeT, WgenT);
    k_gate1<<<dim3(16, 2, 8), 256, 0, stream>>>(dkp, ccd, Wg1, h_pre);
    k_gate2<<<64, 256, 0, stream>>>(h_pre, cyc, Wg1, bg1, Wg2, bg2, gates, cnt, rows);
    k_moe<<<dim3(32, 9, KSPLIT), 256, 0, stream>>>(xfb, WeT, WgenT, be, gates, cnt, rows, comb, gen);
    k_final<<<(B_ * 128) / 256, 256, 0, stream>>>(gen, comb, bgen, out);
}

// Round 2
// 762.860 us; speedup vs baseline: 1.1862x; 1.1862x over previous
//
#include <hip/hip_runtime.h>
#include <hip/hip_bf16.h>
#include <stdint.h>

#define B_    2048
#define F_    12800
#define DLLM_ 768
#define DFF_  256
#define E_    8
#define GIN_K (DLLM_ + F_)   // 13568 virtual K (cycle column handled as rank-1 in gate2)
#define G1Z   32             // gate1 split-K chunks
#define MKSPLIT 8
#define MKPER (F_ / MKSPLIT) // 1600
#define BK    64

typedef __bf16 bf16x8 __attribute__((ext_vector_type(8)));
typedef float  f32x4  __attribute__((ext_vector_type(4)));

__device__ __forceinline__ unsigned short f2bf(float f) {
    unsigned int u = __float_as_uint(f);
    u += 0x7fffu + ((u >> 16) & 1u);           // RNE (inputs are normal floats)
    return (unsigned short)(u >> 16);
}

// ---------------- fp32 -> bf16 flat convert (xf) ----------------
__global__ __launch_bounds__(256) void k_convert(const float* __restrict__ src,
                                                 unsigned short* __restrict__ dst, int n4) {
    int i = blockIdx.x * 256 + threadIdx.x;
    if (i >= n4) return;
    float4 v = ((const float4*)src)[i];
    ushort4 o;
    o.x = f2bf(v.x); o.y = f2bf(v.y); o.z = f2bf(v.z); o.w = f2bf(v.w);
    ((ushort4*)dst)[i] = o;
}

// ------------- transpose+convert We [e][K][128] -> WeT [e][128][K], Wgen likewise -------------
__global__ __launch_bounds__(256) void k_transpose_bf16(const float* __restrict__ We,
                                                        const float* __restrict__ Wgen,
                                                        unsigned short* __restrict__ WeT,
                                                        unsigned short* __restrict__ WgenT) {
    __shared__ float t[32][33];
    int z = blockIdx.z;
    const float* src = (z < 8) ? (We + (size_t)z * F_ * 128) : Wgen;
    unsigned short* dst = (z < 8) ? (WeT + (size_t)z * 128 * F_) : WgenT;
    int k0 = blockIdx.x * 32, n0 = blockIdx.y * 32;
    int tx = threadIdx.x, ty = threadIdx.y;  // 32 x 8
#pragma unroll
    for (int i = 0; i < 4; i++) {
        int k = k0 + ty + i * 8;
        t[ty + i * 8][tx] = src[(size_t)k * 128 + n0 + tx];
    }
    __syncthreads();
#pragma unroll
    for (int i = 0; i < 4; i++) {
        int n = n0 + ty + i * 8;
        dst[(size_t)n * F_ + k0 + tx] = f2bf(t[tx][ty + i * 8]);
    }
}

// ---------------- gate layer-1: h_pre += A @ Wg1 (fp32, split-K atomics) ----------------
__global__ __launch_bounds__(256) void k_gate1(const float* __restrict__ dkp,
                                               const float* __restrict__ xf,
                                               const float* __restrict__ Wg1,
                                               float* __restrict__ h_pre) {
    __shared__ float As[16][132];  // [k][m], padded
    __shared__ float Bs[16][132];  // [k][n], padded
    int m0 = blockIdx.x * 128;
    int n0 = blockIdx.y * 128;
    // 848 total 16-k iterations split unevenly over 32 chunks: 16x27 + 16x26
    int s = blockIdx.z;
    int it0 = s * 26 + (s < 16 ? s : 16);
    int nit = 26 + (s < 16 ? 1 : 0);
    int kbeg = it0 * 16, kend = kbeg + nit * 16;
    int t = threadIdx.x;
    int tx = t & 15, ty = t >> 4;

    float acc[8][8];
#pragma unroll
    for (int i = 0; i < 8; i++)
#pragma unroll
        for (int j = 0; j < 8; j++) acc[i][j] = 0.f;

    int lm = t >> 2;           // 0..63
    int lkq = (t & 3) * 4;     // 0,4,8,12
    int br = t >> 5;           // 0..7
    int bc = (t & 31) * 4;     // 0..124

    float4 aReg[2], bReg[2];
    auto preload = [&](int k) {
        const float* Ab; int astr, aoff, wr0;
        if (k < DLLM_) { Ab = dkp; astr = DLLM_; aoff = k; wr0 = k; }
        else           { Ab = xf;  astr = F_;    aoff = k - DLLM_; wr0 = k + 1; }
#pragma unroll
        for (int p = 0; p < 2; p++)
            aReg[p] = *(const float4*)&Ab[(size_t)(m0 + p * 64 + lm) * astr + aoff + lkq];
#pragma unroll
        for (int p = 0; p < 2; p++)
            bReg[p] = *(const float4*)&Wg1[(size_t)(wr0 + p * 8 + br) * 256 + n0 + bc];
    };
    preload(kbeg);
    for (int k = kbeg; k < kend; k += 16) {
        __syncthreads();
#pragma unroll
        for (int p = 0; p < 2; p++) {
            As[lkq + 0][p * 64 + lm] = aReg[p].x;
            As[lkq + 1][p * 64 + lm] = aReg[p].y;
            As[lkq + 2][p * 64 + lm] = aReg[p].z;
            As[lkq + 3][p * 64 + lm] = aReg[p].w;
            *(float4*)&Bs[p * 8 + br][bc] = bReg[p];
        }
        __syncthreads();
        if (k + 16 < kend) preload(k + 16);
#pragma unroll
        for (int kk = 0; kk < 16; kk++) {
            float4 a0 = *(const float4*)&As[kk][ty * 4];
            float4 a1 = *(const float4*)&As[kk][64 + ty * 4];
            float4 b0 = *(const float4*)&Bs[kk][tx * 4];
            float4 b1 = *(const float4*)&Bs[kk][64 + tx * 4];
            float av[8] = {a0.x, a0.y, a0.z, a0.w, a1.x, a1.y, a1.z, a1.w};
            float bv[8] = {b0.x, b0.y, b0.z, b0.w, b1.x, b1.y, b1.z, b1.w};
#pragma unroll
            for (int i = 0; i < 8; i++)
#pragma unroll
                for (int j = 0; j < 8; j++) acc[i][j] = fmaf(av[i], bv[j], acc[i][j]);
        }
    }
#pragma unroll
    for (int i = 0; i < 8; i++) {
        int row = m0 + ((i < 4) ? (ty * 4 + i) : (64 + ty * 4 + i - 4));
#pragma unroll
        for (int j = 0; j < 8; j++) {
            int col = n0 + ((j < 4) ? (tx * 4 + j) : (64 + tx * 4 + j - 4));
            atomicAdd(&h_pre[(size_t)row * 256 + col], acc[i][j]);
        }
    }
}

// ---------------- gate layer-2: gelu, logits, top-2, gates, expert row lists ----------------
__global__ __launch_bounds__(256) void k_gate2(const float* __restrict__ h_pre,
                                               const float* __restrict__ cyc,
                                               const float* __restrict__ Wg1,
                                               const float* __restrict__ bg1,
                                               const float* __restrict__ Wg2,
                                               const float* __restrict__ bg2,
                                               float* __restrict__ gates,
                                               unsigned int* __restrict__ cnt,
                                               unsigned int* __restrict__ rows) {
    __shared__ float hs[8 * 257];
    __shared__ float w2s[256 * 8];
    __shared__ float ls[8][9];
    int r0 = blockIdx.x * 8;
    int t = threadIdx.x;
    const float* w768 = Wg1 + (size_t)DLLM_ * 256;
    float wc = w768[t], b1c = bg1[t];
#pragma unroll
    for (int i = 0; i < 8; i++) {
        float x = h_pre[(size_t)(r0 + i) * 256 + t] + cyc[r0 + i] * wc + b1c;
        float x3 = x * x * x;
        float g = 0.5f * x * (1.f + tanhf(0.7978845608028654f * (x + 0.044715f * x3)));
        hs[i * 257 + t] = g;
    }
#pragma unroll
    for (int i = 0; i < 8; i++) w2s[i * 256 + t] = Wg2[i * 256 + t];
    __syncthreads();
    if (t < 64) {
        int r = t >> 3, e = t & 7;
        float s = bg2[e];
        for (int k2 = 0; k2 < 256; k2++) s = fmaf(hs[r * 257 + k2], w2s[k2 * 8 + e], s);
        ls[r][e] = s;
    }
    __syncthreads();
    if (t < 8) {
        float l[8];
#pragma unroll
        for (int e = 0; e < 8; e++) l[e] = ls[t][e];
        int i1 = 0; float v1 = l[0];
#pragma unroll
        for (int e = 1; e < 8; e++) if (l[e] > v1) { v1 = l[e]; i1 = e; }
        int i2 = -1; float v2 = -3.0e38f;
#pragma unroll
        for (int e = 0; e < 8; e++) if (e != i1 && l[e] > v2) { v2 = l[e]; i2 = e; }
        float p[8], ps = 0.f;
#pragma unroll
        for (int e = 0; e < 8; e++) { p[e] = expf(l[e] - v1); ps += p[e]; }
        float msum = (p[i1] + p[i2]) / ps;
        float gi = 1.f / (msum + 1e-9f);
        int row = r0 + t;
#pragma unroll
        for (int e = 0; e < 8; e++) {
            float ge = (e == i1 || e == i2) ? (p[e] / ps) * gi : 0.f;
            gates[row * 8 + e] = ge;
        }
        unsigned int s1 = atomicAdd(&cnt[i1], 1u); rows[i1 * 2048 + s1] = (unsigned int)row;
        unsigned int s2 = atomicAdd(&cnt[i2], 1u); rows[i2 * 2048 + s2] = (unsigned int)row;
    }
}

// ---------------- grouped expert GEMM + general GEMM (bf16 MFMA 16x16x32, BK=64) ----------------
__global__ __launch_bounds__(256) void k_moe(const unsigned short* __restrict__ xfb,
                                             const unsigned short* __restrict__ WeT,
                                             const unsigned short* __restrict__ WgenT,
                                             const float* __restrict__ be,
                                             const float* __restrict__ gates,
                                             const unsigned int* __restrict__ cnt,
                                             const unsigned int* __restrict__ rows,
                                             float* __restrict__ comb,
                                             float* __restrict__ gen) {
    __shared__ unsigned short As[64 * 72];    // [row][8 groups * 8 + pad(8)]
    __shared__ unsigned short Bs[128 * 72];   // [col][8 groups * 8 + pad(8)]
    __shared__ unsigned int rowid_s[64];
    int e = blockIdx.y, tile = blockIdx.x, split = blockIdx.z;
    int n_rows = (e < 8) ? (int)cnt[e] : 2048;
    if (tile * 64 >= n_rows) return;
    int t = threadIdx.x;
    if (t < 64) {
        int m = tile * 64 + t;
        unsigned int row = (e < 8) ? ((m < n_rows) ? rows[e * 2048 + m] : rows[e * 2048])
                                   : (unsigned int)m;
        rowid_s[t] = row;
    }
    __syncthreads();
    const unsigned short* WT = (e < 8) ? (WeT + (size_t)e * 128 * F_) : WgenT;
    int k0 = split * MKPER;

    // A staging: 4 lanes cover one row's 64 k-elems as 2x(4x16B contiguous)
    int arow = t >> 2, akq = t & 3;
    const unsigned short* aptr = xfb + (size_t)rowid_s[arow] * F_ + k0 + akq * 8;
    unsigned short* asd0 = &As[arow * 72 + akq * 8];
    unsigned short* asd1 = &As[arow * 72 + (akq + 4) * 8];
    // B staging: 2 lanes cover one col's 64 k-elems as 2x(64B contiguous)
    int bcol = t >> 1, bh = t & 1;
    const unsigned short* bptr = WT + (size_t)bcol * F_ + k0 + bh * 32;
    unsigned short* bsd = &Bs[bcol * 72 + bh * 32];

    int lane = t & 63;
    int lm = lane & 15, lg = lane >> 4;
    int wave = t >> 6, wr = wave >> 1, wc2 = wave & 1;  // 2x2 wave grid, each 32x64

    f32x4 acc[2][4];
#pragma unroll
    for (int i = 0; i < 2; i++)
#pragma unroll
        for (int j = 0; j < 4; j++) acc[i][j] = (f32x4){0.f, 0.f, 0.f, 0.f};

    uint4 ra0 = *(const uint4*)aptr;
    uint4 ra1 = *(const uint4*)(aptr + 32);
    uint4 rb0 = *(const uint4*)(bptr);
    uint4 rb1 = *(const uint4*)(bptr + 8);
    uint4 rb2 = *(const uint4*)(bptr + 16);
    uint4 rb3 = *(const uint4*)(bptr + 24);
    for (int kk = 0; kk < MKPER; kk += BK) {
        __syncthreads();
        *(uint4*)asd0 = ra0;
        *(uint4*)asd1 = ra1;
        *(uint4*)(bsd)      = rb0;
        *(uint4*)(bsd + 8)  = rb1;
        *(uint4*)(bsd + 16) = rb2;
        *(uint4*)(bsd + 24) = rb3;
        __syncthreads();
        if (kk + BK < MKPER) {
            aptr += BK; bptr += BK;
            ra0 = *(const uint4*)aptr;
            ra1 = *(const uint4*)(aptr + 32);
            rb0 = *(const uint4*)(bptr);
            rb1 = *(const uint4*)(bptr + 8);
            rb2 = *(const uint4*)(bptr + 16);
            rb3 = *(const uint4*)(bptr + 24);
        }
#pragma unroll
        for (int kb = 0; kb < 2; kb++) {
            bf16x8 af[2], bfr[4];
#pragma unroll
            for (int mt = 0; mt < 2; mt++)
                af[mt] = *(const bf16x8*)&As[(wr * 32 + mt * 16 + lm) * 72 + (kb * 4 + lg) * 8];
#pragma unroll
            for (int nt = 0; nt < 4; nt++)
                bfr[nt] = *(const bf16x8*)&Bs[(wc2 * 64 + nt * 16 + lm) * 72 + (kb * 4 + lg) * 8];
#pragma unroll
            for (int mt = 0; mt < 2; mt++)
#pragma unroll
                for (int nt = 0; nt < 4; nt++)
                    acc[mt][nt] = __builtin_amdgcn_mfma_f32_16x16x32_bf16(af[mt], bfr[nt], acc[mt][nt], 0, 0, 0);
        }
    }
#pragma unroll
    for (int mt = 0; mt < 2; mt++) {
        int rl0 = wr * 32 + mt * 16 + lg * 4;
#pragma unroll
        for (int nt = 0; nt < 4; nt++) {
            int col = wc2 * 64 + nt * 16 + lm;
#pragma unroll
            for (int r = 0; r < 4; r++) {
                int rloc = rl0 + r;
                float v = acc[mt][nt][r];
                if (e < 8) {
                    if (tile * 64 + rloc < n_rows) {
                        unsigned int grow = rowid_s[rloc];
                        float g = gates[grow * 8 + e];
                        float bias = (split == 0) ? be[e * 128 + col] : 0.f;
                        atomicAdd(&comb[(size_t)grow * 128 + col], g * (v + bias));
                    }
                } else {
                    atomicAdd(&gen[(size_t)(tile * 64 + rloc) * 128 + col], v);
                }
            }
        }
    }
}

// ---------------- finalize: out = gen + bgen + f32(bf16(comb)) ----------------
__global__ __launch_bounds__(256) void k_final(const float* __restrict__ gen,
                                               const float* __restrict__ comb,
                                               const float* __restrict__ bgen,
                                               float* __restrict__ out) {
    int i = blockIdx.x * 256 + threadIdx.x;
    float g = gen[i] + bgen[i & 127];
    unsigned short cb = f2bf(comb[i]);
    float c = __uint_as_float(((unsigned int)cb) << 16);
    out[i] = g + c;
}

extern "C" void kernel_launch(void* const* d_in, const int* in_sizes, int n_in,
                              void* d_out, int out_size, void* d_ws, size_t ws_size,
                              hipStream_t stream) {
    (void)in_sizes; (void)n_in; (void)out_size; (void)ws_size;
    const float* ccd  = (const float*)d_in[0];
    const float* cyc  = (const float*)d_in[1];
    const float* dkp  = (const float*)d_in[2];
    const float* Wg1  = (const float*)d_in[3];
    const float* bg1  = (const float*)d_in[4];
    const float* Wg2  = (const float*)d_in[5];
    const float* bg2  = (const float*)d_in[6];
    const float* We   = (const float*)d_in[7];
    const float* be   = (const float*)d_in[8];
    const float* Wgen = (const float*)d_in[9];
    const float* bgen = (const float*)d_in[10];
    float* out = (float*)d_out;

    char* ws = (char*)d_ws;
    size_t o = 0;
    unsigned short* xfb   = (unsigned short*)(ws + o); o += (size_t)B_ * F_ * 2;        // 52.4 MB
    unsigned short* WeT   = (unsigned short*)(ws + o); o += (size_t)E_ * 128 * F_ * 2;  // 26.2 MB
    unsigned short* WgenT = (unsigned short*)(ws + o); o += (size_t)128 * F_ * 2;       // 3.3 MB
    float* h_pre = (float*)(ws + o); o += (size_t)B_ * 256 * 4;                          // 2.1 MB
    float* gates = (float*)(ws + o); o += (size_t)B_ * 8 * 4;
    unsigned int* cnt = (unsigned int*)(ws + o); o += 256;
    unsigned int* rows = (unsigned int*)(ws + o); o += (size_t)8 * 2048 * 4;
    float* comb = (float*)(ws + o); o += (size_t)B_ * 128 * 4;
    float* gen  = (float*)(ws + o); o += (size_t)B_ * 128 * 4;

    hipMemsetAsync(h_pre, 0, (size_t)B_ * 256 * 4, stream);
    hipMemsetAsync(comb, 0, (size_t)B_ * 128 * 4, stream);
    hipMemsetAsync(gen,  0, (size_t)B_ * 128 * 4, stream);
    hipMemsetAsync(cnt,  0, 32, stream);

    k_convert<<<(B_ * F_ / 4) / 256, 256, 0, stream>>>(ccd, xfb, B_ * F_ / 4);
    k_transpose_bf16<<<dim3(F_ / 32, 4, 9), dim3(32, 8, 1), 0, stream>>>(We, Wgen, WeT, WgenT);
    k_gate1<<<dim3(16, 2, G1Z), 256, 0, stream>>>(dkp, ccd, Wg1, h_pre);
    k_gate2<<<B_ / 8, 256, 0, stream>>>(h_pre, cyc, Wg1, bg1, Wg2, bg2, gates, cnt, rows);
    k_moe<<<dim3(32, 9, MKSPLIT), 256, 0, stream>>>(xfb, WeT, WgenT, be, gates, cnt, rows, comb, gen);
    k_final<<<(B_ * 128) / 256, 256, 0, stream>>>(gen, comb, bgen, out);
}

// Round 3
// 652.074 us; speedup vs baseline: 1.3877x; 1.1699x over previous
//
#include <hip/hip_runtime.h>
#include <hip/hip_bf16.h>
#include <stdint.h>

#define B_    2048
#define F_    12800
#define DLLM_ 768
#define E_    8
#define G1Z   32             // gate1 split-K chunks (partial buffers)
#define MKSPLIT 8
#define MKPER (F_ / MKSPLIT) // 1600
#define BK    64

typedef __bf16 bf16x8 __attribute__((ext_vector_type(8)));
typedef float  f32x4  __attribute__((ext_vector_type(4)));

__device__ __forceinline__ unsigned short f2bf(float f) {
    unsigned int u = __float_as_uint(f);
    u += 0x7fffu + ((u >> 16) & 1u);           // RNE (inputs are normal floats)
    return (unsigned short)(u >> 16);
}

// ---------------- fp32 -> bf16 flat convert (xf) ----------------
__global__ __launch_bounds__(256) void k_convert(const float* __restrict__ src,
                                                 unsigned short* __restrict__ dst, int n4) {
    int i = blockIdx.x * 256 + threadIdx.x;
    if (i >= n4) return;
    float4 v = ((const float4*)src)[i];
    ushort4 o;
    o.x = f2bf(v.x); o.y = f2bf(v.y); o.z = f2bf(v.z); o.w = f2bf(v.w);
    ((ushort4*)dst)[i] = o;
}

// ------------- transpose+convert We [e][K][128] -> WeT [e][128][K], Wgen likewise -------------
__global__ __launch_bounds__(256) void k_transpose_bf16(const float* __restrict__ We,
                                                        const float* __restrict__ Wgen,
                                                        unsigned short* __restrict__ WeT,
                                                        unsigned short* __restrict__ WgenT) {
    __shared__ float t[32][33];
    int z = blockIdx.z;
    const float* src = (z < 8) ? (We + (size_t)z * F_ * 128) : Wgen;
    unsigned short* dst = (z < 8) ? (WeT + (size_t)z * 128 * F_) : WgenT;
    int k0 = blockIdx.x * 32, n0 = blockIdx.y * 32;
    int tx = threadIdx.x, ty = threadIdx.y;  // 32 x 8
#pragma unroll
    for (int i = 0; i < 4; i++) {
        int k = k0 + ty + i * 8;
        t[ty + i * 8][tx] = src[(size_t)k * 128 + n0 + tx];
    }
    __syncthreads();
#pragma unroll
    for (int i = 0; i < 4; i++) {
        int n = n0 + ty + i * 8;
        dst[(size_t)n * F_ + k0 + tx] = f2bf(t[tx][ty + i * 8]);
    }
}

// -------- gate layer-1: h_part[s] = A-chunk @ Wg1-chunk (fp32, 128x256 block, 16x8 thread tile) --------
__global__ __launch_bounds__(256, 2) void k_gate1(const float* __restrict__ dkp,
                                                  const float* __restrict__ xf,
                                                  const float* __restrict__ Wg1,
                                                  float* __restrict__ h_part,
                                                  int nparts) {
    __shared__ float As[16][132];   // [k][m]
    __shared__ float Bs[16][260];   // [k][n]
    int m0 = blockIdx.x * 128;
    int s = blockIdx.y;
    // 848 total 16-k iters split 16x27 + 16x26
    int it0 = s * 26 + (s < 16 ? s : 16);
    int nit = 26 + (s < 16 ? 1 : 0);
    int t = threadIdx.x;
    int tm = t >> 5;      // 0..7  (m-group of 16 rows)
    int tn = t & 31;      // 0..31 (n-group of 8 cols)

    float acc[16][8];
#pragma unroll
    for (int i = 0; i < 16; i++)
#pragma unroll
        for (int j = 0; j < 8; j++) acc[i][j] = 0.f;

    int arow = t >> 2, akq = (t & 3) * 4;   // A: 2 float4/thread (rows arow, arow+64)
    int bkr = t >> 6, bcol = (t & 63) * 4;  // B: 4 float4/thread (k-rows bkr+4r)

    float4 aR[2], bR[4];
    auto preload = [&](int k) {
        const float* Ab; int astr, aoff, wr0;
        if (k < DLLM_) { Ab = dkp; astr = DLLM_; aoff = k; wr0 = k; }
        else           { Ab = xf;  astr = F_;    aoff = k - DLLM_; wr0 = k + 1; }
        aR[0] = *(const float4*)&Ab[(size_t)(m0 + arow) * astr + aoff + akq];
        aR[1] = *(const float4*)&Ab[(size_t)(m0 + arow + 64) * astr + aoff + akq];
#pragma unroll
        for (int r = 0; r < 4; r++)
            bR[r] = *(const float4*)&Wg1[(size_t)(wr0 + bkr + r * 4) * 256 + bcol];
    };
    preload(it0 * 16);
    for (int it = 0; it < nit; it++) {
        __syncthreads();
        {
            float a0[4] = {aR[0].x, aR[0].y, aR[0].z, aR[0].w};
            float a1[4] = {aR[1].x, aR[1].y, aR[1].z, aR[1].w};
#pragma unroll
            for (int j = 0; j < 4; j++) {
                As[akq + j][arow]      = a0[j];
                As[akq + j][arow + 64] = a1[j];
            }
#pragma unroll
            for (int r = 0; r < 4; r++)
                *(float4*)&Bs[bkr + r * 4][bcol] = bR[r];
        }
        __syncthreads();
        if (it + 1 < nit) preload((it0 + it + 1) * 16);
#pragma unroll 4
        for (int kk = 0; kk < 16; kk++) {
            float4 a0 = *(const float4*)&As[kk][tm * 16];
            float4 a1 = *(const float4*)&As[kk][tm * 16 + 4];
            float4 a2 = *(const float4*)&As[kk][tm * 16 + 8];
            float4 a3 = *(const float4*)&As[kk][tm * 16 + 12];
            float4 b0 = *(const float4*)&Bs[kk][tn * 8];
            float4 b1 = *(const float4*)&Bs[kk][tn * 8 + 4];
            float av[16] = {a0.x, a0.y, a0.z, a0.w, a1.x, a1.y, a1.z, a1.w,
                            a2.x, a2.y, a2.z, a2.w, a3.x, a3.y, a3.z, a3.w};
            float bv[8]  = {b0.x, b0.y, b0.z, b0.w, b1.x, b1.y, b1.z, b1.w};
#pragma unroll
            for (int i = 0; i < 16; i++)
#pragma unroll
                for (int j = 0; j < 8; j++) acc[i][j] = fmaf(av[i], bv[j], acc[i][j]);
        }
    }
    // epilogue
    if (nparts > 1) {
        float* dst = h_part + (size_t)s * B_ * 256;
#pragma unroll
        for (int i = 0; i < 16; i++) {
            size_t base = (size_t)(m0 + tm * 16 + i) * 256 + tn * 8;
            *(float4*)&dst[base]     = (float4){acc[i][0], acc[i][1], acc[i][2], acc[i][3]};
            *(float4*)&dst[base + 4] = (float4){acc[i][4], acc[i][5], acc[i][6], acc[i][7]};
        }
    } else {
#pragma unroll
        for (int i = 0; i < 16; i++) {
            size_t base = (size_t)(m0 + tm * 16 + i) * 256 + tn * 8;
#pragma unroll
            for (int j = 0; j < 8; j++) atomicAdd(&h_part[base + j], acc[i][j]);
        }
    }
}

// ---------------- gate layer-2: reduce partials, gelu, logits, top-2, gates, row lists ----------------
__global__ __launch_bounds__(256) void k_gate2(const float* __restrict__ h_part,
                                               const float* __restrict__ cyc,
                                               const float* __restrict__ Wg1,
                                               const float* __restrict__ bg1,
                                               const float* __restrict__ Wg2,
                                               const float* __restrict__ bg2,
                                               float* __restrict__ gates,
                                               unsigned int* __restrict__ cnt,
                                               unsigned int* __restrict__ rows,
                                               int nparts) {
    __shared__ float hs[8 * 257];
    __shared__ float w2s[256 * 8];
    __shared__ float ls[8][9];
    int r0 = blockIdx.x * 8;
    int t = threadIdx.x;
    const float* w768 = Wg1 + (size_t)DLLM_ * 256;
    float wc = w768[t], b1c = bg1[t];
#pragma unroll
    for (int i = 0; i < 8; i++) {
        size_t idx = (size_t)(r0 + i) * 256 + t;
        float x = 0.f;
        for (int p = 0; p < nparts; p++) x += h_part[(size_t)p * B_ * 256 + idx];
        x += cyc[r0 + i] * wc + b1c;
        float x3 = x * x * x;
        float g = 0.5f * x * (1.f + tanhf(0.7978845608028654f * (x + 0.044715f * x3)));
        hs[i * 257 + t] = g;
    }
#pragma unroll
    for (int i = 0; i < 8; i++) w2s[i * 256 + t] = Wg2[i * 256 + t];
    __syncthreads();
    if (t < 64) {
        int r = t >> 3, e = t & 7;
        float s = bg2[e];
        for (int k2 = 0; k2 < 256; k2++) s = fmaf(hs[r * 257 + k2], w2s[k2 * 8 + e], s);
        ls[r][e] = s;
    }
    __syncthreads();
    if (t < 8) {
        float l[8];
#pragma unroll
        for (int e = 0; e < 8; e++) l[e] = ls[t][e];
        int i1 = 0; float v1 = l[0];
#pragma unroll
        for (int e = 1; e < 8; e++) if (l[e] > v1) { v1 = l[e]; i1 = e; }
        int i2 = -1; float v2 = -3.0e38f;
#pragma unroll
        for (int e = 0; e < 8; e++) if (e != i1 && l[e] > v2) { v2 = l[e]; i2 = e; }
        float p[8], ps = 0.f;
#pragma unroll
        for (int e = 0; e < 8; e++) { p[e] = expf(l[e] - v1); ps += p[e]; }
        float msum = (p[i1] + p[i2]) / ps;
        float gi = 1.f / (msum + 1e-9f);
        int row = r0 + t;
#pragma unroll
        for (int e = 0; e < 8; e++) {
            float ge = (e == i1 || e == i2) ? (p[e] / ps) * gi : 0.f;
            gates[row * 8 + e] = ge;
        }
        unsigned int s1 = atomicAdd(&cnt[i1], 1u); rows[i1 * 2048 + s1] = (unsigned int)row;
        unsigned int s2 = atomicAdd(&cnt[i2], 1u); rows[i2 * 2048 + s2] = (unsigned int)row;
    }
}

// ---------------- grouped expert GEMM + general GEMM (bf16 MFMA 16x16x32, BK=64) ----------------
__global__ __launch_bounds__(256) void k_moe(const unsigned short* __restrict__ xfb,
                                             const unsigned short* __restrict__ WeT,
                                             const unsigned short* __restrict__ WgenT,
                                             const float* __restrict__ be,
                                             const float* __restrict__ gates,
                                             const unsigned int* __restrict__ cnt,
                                             const unsigned int* __restrict__ rows,
                                             float* __restrict__ comb,
                                             float* __restrict__ gen) {
    __shared__ unsigned short As[64 * 72];    // [row][8 groups * 8 + pad(8)]
    __shared__ unsigned short Bs[128 * 72];   // [col][8 groups * 8 + pad(8)]
    __shared__ unsigned int rowid_s[64];
    int e = blockIdx.y, tile = blockIdx.x, split = blockIdx.z;
    int n_rows = (e < 8) ? (int)cnt[e] : 2048;
    if (tile * 64 >= n_rows) return;
    int t = threadIdx.x;
    if (t < 64) {
        int m = tile * 64 + t;
        unsigned int row = (e < 8) ? ((m < n_rows) ? rows[e * 2048 + m] : rows[e * 2048])
                                   : (unsigned int)m;
        rowid_s[t] = row;
    }
    __syncthreads();
    const unsigned short* WT = (e < 8) ? (WeT + (size_t)e * 128 * F_) : WgenT;
    int k0 = split * MKPER;

    int arow = t >> 2, akq = t & 3;
    const unsigned short* aptr = xfb + (size_t)rowid_s[arow] * F_ + k0 + akq * 8;
    unsigned short* asd0 = &As[arow * 72 + akq * 8];
    unsigned short* asd1 = &As[arow * 72 + (akq + 4) * 8];
    int bcol = t >> 1, bh = t & 1;
    const unsigned short* bptr = WT + (size_t)bcol * F_ + k0 + bh * 32;
    unsigned short* bsd = &Bs[bcol * 72 + bh * 32];

    int lane = t & 63;
    int lm = lane & 15, lg = lane >> 4;
    int wave = t >> 6, wr = wave >> 1, wc2 = wave & 1;  // 2x2 wave grid, each 32x64

    f32x4 acc[2][4];
#pragma unroll
    for (int i = 0; i < 2; i++)
#pragma unroll
        for (int j = 0; j < 4; j++) acc[i][j] = (f32x4){0.f, 0.f, 0.f, 0.f};

    uint4 ra0 = *(const uint4*)aptr;
    uint4 ra1 = *(const uint4*)(aptr + 32);
    uint4 rb0 = *(const uint4*)(bptr);
    uint4 rb1 = *(const uint4*)(bptr + 8);
    uint4 rb2 = *(const uint4*)(bptr + 16);
    uint4 rb3 = *(const uint4*)(bptr + 24);
    for (int kk = 0; kk < MKPER; kk += BK) {
        __syncthreads();
        *(uint4*)asd0 = ra0;
        *(uint4*)asd1 = ra1;
        *(uint4*)(bsd)      = rb0;
        *(uint4*)(bsd + 8)  = rb1;
        *(uint4*)(bsd + 16) = rb2;
        *(uint4*)(bsd + 24) = rb3;
        __syncthreads();
        if (kk + BK < MKPER) {
            aptr += BK; bptr += BK;
            ra0 = *(const uint4*)aptr;
            ra1 = *(const uint4*)(aptr + 32);
            rb0 = *(const uint4*)(bptr);
            rb1 = *(const uint4*)(bptr + 8);
            rb2 = *(const uint4*)(bptr + 16);
            rb3 = *(const uint4*)(bptr + 24);
        }
#pragma unroll
        for (int kb = 0; kb < 2; kb++) {
            bf16x8 af[2], bfr[4];
#pragma unroll
            for (int mt = 0; mt < 2; mt++)
                af[mt] = *(const bf16x8*)&As[(wr * 32 + mt * 16 + lm) * 72 + (kb * 4 + lg) * 8];
#pragma unroll
            for (int nt = 0; nt < 4; nt++)
                bfr[nt] = *(const bf16x8*)&Bs[(wc2 * 64 + nt * 16 + lm) * 72 + (kb * 4 + lg) * 8];
#pragma unroll
            for (int mt = 0; mt < 2; mt++)
#pragma unroll
                for (int nt = 0; nt < 4; nt++)
                    acc[mt][nt] = __builtin_amdgcn_mfma_f32_16x16x32_bf16(af[mt], bfr[nt], acc[mt][nt], 0, 0, 0);
        }
    }
#pragma unroll
    for (int mt = 0; mt < 2; mt++) {
        int rl0 = wr * 32 + mt * 16 + lg * 4;
#pragma unroll
        for (int nt = 0; nt < 4; nt++) {
            int col = wc2 * 64 + nt * 16 + lm;
#pragma unroll
            for (int r = 0; r < 4; r++) {
                int rloc = rl0 + r;
                float v = acc[mt][nt][r];
                if (e < 8) {
                    if (tile * 64 + rloc < n_rows) {
                        unsigned int grow = rowid_s[rloc];
                        float g = gates[grow * 8 + e];
                        float bias = (split == 0) ? be[e * 128 + col] : 0.f;
                        atomicAdd(&comb[(size_t)grow * 128 + col], g * (v + bias));
                    }
                } else {
                    atomicAdd(&gen[(size_t)(tile * 64 + rloc) * 128 + col], v);
                }
            }
        }
    }
}

// ---------------- finalize: out = gen + bgen + f32(bf16(comb)) ----------------
__global__ __launch_bounds__(256) void k_final(const float* __restrict__ gen,
                                               const float* __restrict__ comb,
                                               const float* __restrict__ bgen,
                                               float* __restrict__ out) {
    int i = blockIdx.x * 256 + threadIdx.x;
    float g = gen[i] + bgen[i & 127];
    unsigned short cb = f2bf(comb[i]);
    float c = __uint_as_float(((unsigned int)cb) << 16);
    out[i] = g + c;
}

extern "C" void kernel_launch(void* const* d_in, const int* in_sizes, int n_in,
                              void* d_out, int out_size, void* d_ws, size_t ws_size,
                              hipStream_t stream) {
    (void)in_sizes; (void)n_in; (void)out_size;
    const float* ccd  = (const float*)d_in[0];
    const float* cyc  = (const float*)d_in[1];
    const float* dkp  = (const float*)d_in[2];
    const float* Wg1  = (const float*)d_in[3];
    const float* bg1  = (const float*)d_in[4];
    const float* Wg2  = (const float*)d_in[5];
    const float* bg2  = (const float*)d_in[6];
    const float* We   = (const float*)d_in[7];
    const float* be   = (const float*)d_in[8];
    const float* Wgen = (const float*)d_in[9];
    const float* bgen = (const float*)d_in[10];
    float* out = (float*)d_out;

    // base scratch
    char* ws = (char*)d_ws;
    size_t o = 0;
    unsigned short* xfb   = (unsigned short*)(ws + o); o += (size_t)B_ * F_ * 2;        // 52.4 MB
    unsigned short* WeT   = (unsigned short*)(ws + o); o += (size_t)E_ * 128 * F_ * 2;  // 26.2 MB
    unsigned short* WgenT = (unsigned short*)(ws + o); o += (size_t)128 * F_ * 2;       // 3.3 MB
    float* gates = (float*)(ws + o); o += (size_t)B_ * 8 * 4;
    unsigned int* cnt = (unsigned int*)(ws + o); o += 256;
    unsigned int* rows = (unsigned int*)(ws + o); o += (size_t)8 * 2048 * 4;
    float* comb = (float*)(ws + o); o += (size_t)B_ * 128 * 4;
    float* gen  = (float*)(ws + o); o += (size_t)B_ * 128 * 4;
    float* h_part = (float*)(ws + o);
    size_t need_full = o + (size_t)G1Z * B_ * 256 * 4;   // + 67 MB of partials
    int nparts = (ws_size >= need_full) ? G1Z : 1;

    if (nparts == 1)
        hipMemsetAsync(h_part, 0, (size_t)B_ * 256 * 4, stream);
    hipMemsetAsync(comb, 0, (size_t)B_ * 128 * 4, stream);
    hipMemsetAsync(gen,  0, (size_t)B_ * 128 * 4, stream);
    hipMemsetAsync(cnt,  0, 32, stream);

    k_convert<<<(B_ * F_ / 4) / 256, 256, 0, stream>>>(ccd, xfb, B_ * F_ / 4);
    k_transpose_bf16<<<dim3(F_ / 32, 4, 9), dim3(32, 8, 1), 0, stream>>>(We, Wgen, WeT, WgenT);
    k_gate1<<<dim3(16, G1Z), 256, 0, stream>>>(dkp, ccd, Wg1, h_part, nparts);
    k_gate2<<<B_ / 8, 256, 0, stream>>>(h_part, cyc, Wg1, bg1, Wg2, bg2, gates, cnt, rows, nparts);
    k_moe<<<dim3(32, 9, MKSPLIT), 256, 0, stream>>>(xfb, WeT, WgenT, be, gates, cnt, rows, comb, gen);
    k_final<<<(B_ * 128) / 256, 256, 0, stream>>>(gen, comb, bgen, out);
}

// Round 4
// 637.122 us; speedup vs baseline: 1.4203x; 1.0235x over previous
//
#include <hip/hip_runtime.h>
#include <hip/hip_bf16.h>
#include <stdint.h>

#define B_    2048
#define F_    12800
#define DLLM_ 768
#define E_    8
#define G1Z   32             // gate1 split-K chunks (partial buffers)
#define MKSPLIT 8
#define MKPER (F_ / MKSPLIT) // 1600
#define BK    64

typedef __bf16 bf16x8 __attribute__((ext_vector_type(8)));
typedef float  f32x4  __attribute__((ext_vector_type(4)));

__device__ __forceinline__ unsigned short f2bf(float f) {
    unsigned int u = __float_as_uint(f);
    u += 0x7fffu + ((u >> 16) & 1u);           // RNE (inputs are normal floats)
    return (unsigned short)(u >> 16);
}

// ---------------- fp32 -> bf16 flat convert (xf) ----------------
__global__ __launch_bounds__(256) void k_convert(const float* __restrict__ src,
                                                 unsigned short* __restrict__ dst, int n4) {
    int i = blockIdx.x * 256 + threadIdx.x;
    if (i >= n4) return;
    float4 v = ((const float4*)src)[i];
    ushort4 o;
    o.x = f2bf(v.x); o.y = f2bf(v.y); o.z = f2bf(v.z); o.w = f2bf(v.w);
    ((ushort4*)dst)[i] = o;
}

// ------------- transpose+convert We [e][K][128] -> WeT [e][128][K], Wgen likewise -------------
__global__ __launch_bounds__(256) void k_transpose_bf16(const float* __restrict__ We,
                                                        const float* __restrict__ Wgen,
                                                        unsigned short* __restrict__ WeT,
                                                        unsigned short* __restrict__ WgenT) {
    __shared__ float t[32][33];
    int z = blockIdx.z;
    const float* src = (z < 8) ? (We + (size_t)z * F_ * 128) : Wgen;
    unsigned short* dst = (z < 8) ? (WeT + (size_t)z * 128 * F_) : WgenT;
    int k0 = blockIdx.x * 32, n0 = blockIdx.y * 32;
    int tx = threadIdx.x, ty = threadIdx.y;  // 32 x 8
#pragma unroll
    for (int i = 0; i < 4; i++) {
        int k = k0 + ty + i * 8;
        t[ty + i * 8][tx] = src[(size_t)k * 128 + n0 + tx];
    }
    __syncthreads();
#pragma unroll
    for (int i = 0; i < 4; i++) {
        int n = n0 + ty + i * 8;
        dst[(size_t)n * F_ + k0 + tx] = f2bf(t[tx][ty + i * 8]);
    }
}

// -------- gate layer-1: h_part[s] = A-chunk @ Wg1-chunk (fp32, 128x256 block, 16x8 thread tile) --------
// B-fragment is split as cols [tn*4..+3] and [128+tn*4..+3] so lane LDS addresses are
// 16B-consecutive -> conflict-free ds_read_b128 (round-3's tn*8 layout was 4-way conflicted).
__global__ __launch_bounds__(256, 2) void k_gate1(const float* __restrict__ dkp,
                                                  const float* __restrict__ xf,
                                                  const float* __restrict__ Wg1,
                                                  float* __restrict__ h_part,
                                                  int nparts) {
    __shared__ float As[16][132];   // [k][m]
    __shared__ float Bs[16][260];   // [k][n]
    int m0 = blockIdx.x * 128;
    int s = blockIdx.y;
    // 848 total 16-k iters split 16x27 + 16x26
    int it0 = s * 26 + (s < 16 ? s : 16);
    int nit = 26 + (s < 16 ? 1 : 0);
    int t = threadIdx.x;
    int tm = t >> 5;      // 0..7  (m-group of 16 rows)
    int tn = t & 31;      // 0..31 (two 4-col groups)

    float acc[16][8];
#pragma unroll
    for (int i = 0; i < 16; i++)
#pragma unroll
        for (int j = 0; j < 8; j++) acc[i][j] = 0.f;

    int arow = t >> 2, akq = (t & 3) * 4;   // A: 2 float4/thread (rows arow, arow+64)
    int bkr = t >> 6, bcol = (t & 63) * 4;  // B: 4 float4/thread (k-rows bkr+4r)

    float4 aR[2], bR[4];
    auto preload = [&](int k) {
        const float* Ab; int astr, aoff, wr0;
        if (k < DLLM_) { Ab = dkp; astr = DLLM_; aoff = k; wr0 = k; }
        else           { Ab = xf;  astr = F_;    aoff = k - DLLM_; wr0 = k + 1; }
        aR[0] = *(const float4*)&Ab[(size_t)(m0 + arow) * astr + aoff + akq];
        aR[1] = *(const float4*)&Ab[(size_t)(m0 + arow + 64) * astr + aoff + akq];
#pragma unroll
        for (int r = 0; r < 4; r++)
            bR[r] = *(const float4*)&Wg1[(size_t)(wr0 + bkr + r * 4) * 256 + bcol];
    };
    preload(it0 * 16);
    for (int it = 0; it < nit; it++) {
        __syncthreads();
        {
            float a0[4] = {aR[0].x, aR[0].y, aR[0].z, aR[0].w};
            float a1[4] = {aR[1].x, aR[1].y, aR[1].z, aR[1].w};
#pragma unroll
            for (int j = 0; j < 4; j++) {
                As[akq + j][arow]      = a0[j];
                As[akq + j][arow + 64] = a1[j];
            }
#pragma unroll
            for (int r = 0; r < 4; r++)
                *(float4*)&Bs[bkr + r * 4][bcol] = bR[r];
        }
        __syncthreads();
        if (it + 1 < nit) preload((it0 + it + 1) * 16);
#pragma unroll 4
        for (int kk = 0; kk < 16; kk++) {
            float4 a0 = *(const float4*)&As[kk][tm * 16];
            float4 a1 = *(const float4*)&As[kk][tm * 16 + 4];
            float4 a2 = *(const float4*)&As[kk][tm * 16 + 8];
            float4 a3 = *(const float4*)&As[kk][tm * 16 + 12];
            float4 b0 = *(const float4*)&Bs[kk][tn * 4];
            float4 b1 = *(const float4*)&Bs[kk][128 + tn * 4];
            float av[16] = {a0.x, a0.y, a0.z, a0.w, a1.x, a1.y, a1.z, a1.w,
                            a2.x, a2.y, a2.z, a2.w, a3.x, a3.y, a3.z, a3.w};
            float bv[8]  = {b0.x, b0.y, b0.z, b0.w, b1.x, b1.y, b1.z, b1.w};
#pragma unroll
            for (int i = 0; i < 16; i++)
#pragma unroll
                for (int j = 0; j < 8; j++) acc[i][j] = fmaf(av[i], bv[j], acc[i][j]);
        }
    }
    // epilogue: cols tn*4 (j 0..3) and 128+tn*4 (j 4..7)
    if (nparts > 1) {
        float* dst = h_part + (size_t)s * B_ * 256;
#pragma unroll
        for (int i = 0; i < 16; i++) {
            size_t base = (size_t)(m0 + tm * 16 + i) * 256;
            *(float4*)&dst[base + tn * 4]       = (float4){acc[i][0], acc[i][1], acc[i][2], acc[i][3]};
            *(float4*)&dst[base + 128 + tn * 4] = (float4){acc[i][4], acc[i][5], acc[i][6], acc[i][7]};
        }
    } else {
#pragma unroll
        for (int i = 0; i < 16; i++) {
            size_t base = (size_t)(m0 + tm * 16 + i) * 256;
#pragma unroll
            for (int j = 0; j < 4; j++) atomicAdd(&h_part[base + tn * 4 + j], acc[i][j]);
#pragma unroll
            for (int j = 4; j < 8; j++) atomicAdd(&h_part[base + 128 + tn * 4 + j - 4], acc[i][j]);
        }
    }
}

// ---------------- gate layer-2: reduce partials, gelu, logits, top-2, gates, row lists ----------------
// rows entries encode row | (slot << 16); slot 0 = top-1 expert, slot 1 = top-2.
__global__ __launch_bounds__(256) void k_gate2(const float* __restrict__ h_part,
                                               const float* __restrict__ cyc,
                                               const float* __restrict__ Wg1,
                                               const float* __restrict__ bg1,
                                               const float* __restrict__ Wg2,
                                               const float* __restrict__ bg2,
                                               float* __restrict__ gates,
                                               unsigned int* __restrict__ cnt,
                                               unsigned int* __restrict__ rows,
                                               int nparts) {
    __shared__ float hs[8 * 257];
    __shared__ float w2s[256 * 8];
    __shared__ float ls[8][9];
    int r0 = blockIdx.x * 8;
    int t = threadIdx.x;
    const float* w768 = Wg1 + (size_t)DLLM_ * 256;
    float wc = w768[t], b1c = bg1[t];
#pragma unroll
    for (int i = 0; i < 8; i++) {
        size_t idx = (size_t)(r0 + i) * 256 + t;
        float x = 0.f;
        for (int p = 0; p < nparts; p++) x += h_part[(size_t)p * B_ * 256 + idx];
        x += cyc[r0 + i] * wc + b1c;
        float x3 = x * x * x;
        float g = 0.5f * x * (1.f + tanhf(0.7978845608028654f * (x + 0.044715f * x3)));
        hs[i * 257 + t] = g;
    }
#pragma unroll
    for (int i = 0; i < 8; i++) w2s[i * 256 + t] = Wg2[i * 256 + t];
    __syncthreads();
    if (t < 64) {
        int r = t >> 3, e = t & 7;
        float s = bg2[e];
        for (int k2 = 0; k2 < 256; k2++) s = fmaf(hs[r * 257 + k2], w2s[k2 * 8 + e], s);
        ls[r][e] = s;
    }
    __syncthreads();
    if (t < 8) {
        float l[8];
#pragma unroll
        for (int e = 0; e < 8; e++) l[e] = ls[t][e];
        int i1 = 0; float v1 = l[0];
#pragma unroll
        for (int e = 1; e < 8; e++) if (l[e] > v1) { v1 = l[e]; i1 = e; }
        int i2 = -1; float v2 = -3.0e38f;
#pragma unroll
        for (int e = 0; e < 8; e++) if (e != i1 && l[e] > v2) { v2 = l[e]; i2 = e; }
        float p[8], ps = 0.f;
#pragma unroll
        for (int e = 0; e < 8; e++) { p[e] = expf(l[e] - v1); ps += p[e]; }
        float msum = (p[i1] + p[i2]) / ps;
        float gi = 1.f / (msum + 1e-9f);
        int row = r0 + t;
#pragma unroll
        for (int e = 0; e < 8; e++) {
            float ge = (e == i1 || e == i2) ? (p[e] / ps) * gi : 0.f;
            gates[row * 8 + e] = ge;
        }
        unsigned int s1 = atomicAdd(&cnt[i1], 1u); rows[i1 * 2048 + s1] = (unsigned int)row;
        unsigned int s2 = atomicAdd(&cnt[i2], 1u); rows[i2 * 2048 + s2] = (unsigned int)row | 0x10000u;
    }
}

// ------- grouped expert GEMM + general GEMM (bf16 MFMA 16x16x32, BK=64, atomic-free epilogue) -------
__global__ __launch_bounds__(256) void k_moe(const unsigned short* __restrict__ xfb,
                                             const unsigned short* __restrict__ WeT,
                                             const unsigned short* __restrict__ WgenT,
                                             const float* __restrict__ be,
                                             const float* __restrict__ gates,
                                             const unsigned int* __restrict__ cnt,
                                             const unsigned int* __restrict__ rows,
                                             float* __restrict__ comb_part,   // [16][2048][128] (pflag) or [2048][128]
                                             float* __restrict__ gen_part,    // [8][2048][128]  (pflag) or [2048][128]
                                             int pflag) {
    __shared__ unsigned short As[64 * 72];    // [row][8 groups * 8 + pad(8)]
    __shared__ unsigned short Bs[128 * 72];   // [col][8 groups * 8 + pad(8)]
    __shared__ unsigned int rowid_s[64];
    int e = blockIdx.y, tile = blockIdx.x, split = blockIdx.z;
    int n_rows = (e < 8) ? (int)cnt[e] : 2048;
    if (tile * 64 >= n_rows) return;
    int t = threadIdx.x;
    if (t < 64) {
        int m = tile * 64 + t;
        unsigned int entry = (e < 8) ? ((m < n_rows) ? rows[e * 2048 + m] : rows[e * 2048])
                                     : (unsigned int)m;
        rowid_s[t] = entry;
    }
    __syncthreads();
    const unsigned short* WT = (e < 8) ? (WeT + (size_t)e * 128 * F_) : WgenT;
    int k0 = split * MKPER;

    int arow = t >> 2, akq = t & 3;
    const unsigned short* aptr = xfb + (size_t)(rowid_s[arow] & 0xFFFFu) * F_ + k0 + akq * 8;
    unsigned short* asd0 = &As[arow * 72 + akq * 8];
    unsigned short* asd1 = &As[arow * 72 + (akq + 4) * 8];
    int bcol = t >> 1, bh = t & 1;
    const unsigned short* bptr = WT + (size_t)bcol * F_ + k0 + bh * 32;
    unsigned short* bsd = &Bs[bcol * 72 + bh * 32];

    int lane = t & 63;
    int lm = lane & 15, lg = lane >> 4;
    int wave = t >> 6, wr = wave >> 1, wc2 = wave & 1;  // 2x2 wave grid, each 32x64

    f32x4 acc[2][4];
#pragma unroll
    for (int i = 0; i < 2; i++)
#pragma unroll
        for (int j = 0; j < 4; j++) acc[i][j] = (f32x4){0.f, 0.f, 0.f, 0.f};

    uint4 ra0 = *(const uint4*)aptr;
    uint4 ra1 = *(const uint4*)(aptr + 32);
    uint4 rb0 = *(const uint4*)(bptr);
    uint4 rb1 = *(const uint4*)(bptr + 8);
    uint4 rb2 = *(const uint4*)(bptr + 16);
    uint4 rb3 = *(const uint4*)(bptr + 24);
    for (int kk = 0; kk < MKPER; kk += BK) {
        __syncthreads();
        *(uint4*)asd0 = ra0;
        *(uint4*)asd1 = ra1;
        *(uint4*)(bsd)      = rb0;
        *(uint4*)(bsd + 8)  = rb1;
        *(uint4*)(bsd + 16) = rb2;
        *(uint4*)(bsd + 24) = rb3;
        __syncthreads();
        if (kk + BK < MKPER) {
            aptr += BK; bptr += BK;
            ra0 = *(const uint4*)aptr;
            ra1 = *(const uint4*)(aptr + 32);
            rb0 = *(const uint4*)(bptr);
            rb1 = *(const uint4*)(bptr + 8);
            rb2 = *(const uint4*)(bptr + 16);
            rb3 = *(const uint4*)(bptr + 24);
        }
#pragma unroll
        for (int kb = 0; kb < 2; kb++) {
            bf16x8 af[2], bfr[4];
#pragma unroll
            for (int mt = 0; mt < 2; mt++)
                af[mt] = *(const bf16x8*)&As[(wr * 32 + mt * 16 + lm) * 72 + (kb * 4 + lg) * 8];
#pragma unroll
            for (int nt = 0; nt < 4; nt++)
                bfr[nt] = *(const bf16x8*)&Bs[(wc2 * 64 + nt * 16 + lm) * 72 + (kb * 4 + lg) * 8];
#pragma unroll
            for (int mt = 0; mt < 2; mt++)
#pragma unroll
                for (int nt = 0; nt < 4; nt++)
                    acc[mt][nt] = __builtin_amdgcn_mfma_f32_16x16x32_bf16(af[mt], bfr[nt], acc[mt][nt], 0, 0, 0);
        }
    }
#pragma unroll
    for (int mt = 0; mt < 2; mt++) {
        int rl0 = wr * 32 + mt * 16 + lg * 4;
#pragma unroll
        for (int nt = 0; nt < 4; nt++) {
            int col = wc2 * 64 + nt * 16 + lm;
#pragma unroll
            for (int r = 0; r < 4; r++) {
                int rloc = rl0 + r;
                float v = acc[mt][nt][r];
                if (e < 8) {
                    if (tile * 64 + rloc < n_rows) {
                        unsigned int entry = rowid_s[rloc];
                        unsigned int grow = entry & 0xFFFFu;
                        unsigned int slot = entry >> 16;
                        float g = gates[grow * 8 + e];
                        float bias = (split == 0) ? be[e * 128 + col] : 0.f;
                        float val = g * (v + bias);
                        if (pflag)
                            comb_part[((size_t)(split * 2 + slot) * B_ + grow) * 128 + col] = val;
                        else
                            atomicAdd(&comb_part[(size_t)grow * 128 + col], val);
                    }
                } else {
                    int row = tile * 64 + rloc;
                    if (pflag)
                        gen_part[((size_t)split * B_ + row) * 128 + col] = v;
                    else
                        atomicAdd(&gen_part[(size_t)row * 128 + col], v);
                }
            }
        }
    }
}

// ---------------- finalize: out = sum(gen parts) + bgen + f32(bf16(sum(comb parts))) ----------------
__global__ __launch_bounds__(256) void k_final(const float* __restrict__ gen_part,
                                               const float* __restrict__ comb_part,
                                               const float* __restrict__ bgen,
                                               float* __restrict__ out, int pflag) {
    int i = blockIdx.x * 256 + threadIdx.x;
    float c = 0.f, g = 0.f;
    if (pflag) {
#pragma unroll
        for (int p = 0; p < 16; p++) c += comb_part[(size_t)p * B_ * 128 + i];
#pragma unroll
        for (int p = 0; p < 8; p++) g += gen_part[(size_t)p * B_ * 128 + i];
    } else {
        c = comb_part[i];
        g = gen_part[i];
    }
    unsigned short cb = f2bf(c);
    float cf = __uint_as_float(((unsigned int)cb) << 16);
    out[i] = g + bgen[i & 127] + cf;
}

extern "C" void kernel_launch(void* const* d_in, const int* in_sizes, int n_in,
                              void* d_out, int out_size, void* d_ws, size_t ws_size,
                              hipStream_t stream) {
    (void)in_sizes; (void)n_in; (void)out_size;
    const float* ccd  = (const float*)d_in[0];
    const float* cyc  = (const float*)d_in[1];
    const float* dkp  = (const float*)d_in[2];
    const float* Wg1  = (const float*)d_in[3];
    const float* bg1  = (const float*)d_in[4];
    const float* Wg2  = (const float*)d_in[5];
    const float* bg2  = (const float*)d_in[6];
    const float* We   = (const float*)d_in[7];
    const float* be   = (const float*)d_in[8];
    const float* Wgen = (const float*)d_in[9];
    const float* bgen = (const float*)d_in[10];
    float* out = (float*)d_out;

    // base scratch
    char* ws = (char*)d_ws;
    size_t o = 0;
    unsigned short* xfb   = (unsigned short*)(ws + o); o += (size_t)B_ * F_ * 2;        // 52.4 MB
    unsigned short* WeT   = (unsigned short*)(ws + o); o += (size_t)E_ * 128 * F_ * 2;  // 26.2 MB
    unsigned short* WgenT = (unsigned short*)(ws + o); o += (size_t)128 * F_ * 2;       // 3.3 MB
    float* gates = (float*)(ws + o); o += (size_t)B_ * 8 * 4;
    unsigned int* cnt = (unsigned int*)(ws + o); o += 256;
    unsigned int* rows = (unsigned int*)(ws + o); o += (size_t)8 * 2048 * 4;
    // region R: h_part (gate1/gate2 lifetime) aliases comb/gen partials (moe/final lifetime)
    char* R = ws + o;
    float* h_part    = (float*)R;                                   // up to G1Z * 2.1 MB
    float* comb_part = (float*)R;                                   // 16 * 1.05 MB
    float* gen_part  = (float*)(R + (size_t)16 * B_ * 128 * 4);     // 8 * 1.05 MB
    size_t need_gate  = o + (size_t)G1Z * B_ * 256 * 4;             // ~153 MB total
    size_t need_moe   = o + (size_t)24 * B_ * 128 * 4;              // ~107 MB total
    int nparts = (ws_size >= need_gate) ? G1Z : 1;
    int pflag  = (ws_size >= need_moe) ? 1 : 0;

    if (nparts == 1)
        hipMemsetAsync(h_part, 0, (size_t)B_ * 256 * 4, stream);
    hipMemsetAsync(cnt, 0, 32, stream);

    k_convert<<<(B_ * F_ / 4) / 256, 256, 0, stream>>>(ccd, xfb, B_ * F_ / 4);
    k_transpose_bf16<<<dim3(F_ / 32, 4, 9), dim3(32, 8, 1), 0, stream>>>(We, Wgen, WeT, WgenT);
    k_gate1<<<dim3(16, G1Z), 256, 0, stream>>>(dkp, ccd, Wg1, h_part, nparts);
    k_gate2<<<B_ / 8, 256, 0, stream>>>(h_part, cyc, Wg1, bg1, Wg2, bg2, gates, cnt, rows, nparts);
    if (!pflag) {
        hipMemsetAsync(comb_part, 0, (size_t)B_ * 128 * 4, stream);
        hipMemsetAsync(gen_part,  0, (size_t)B_ * 128 * 4, stream);
    }
    k_moe<<<dim3(32, 9, MKSPLIT), 256, 0, stream>>>(xfb, WeT, WgenT, be, gates, cnt, rows,
                                                    comb_part, gen_part, pflag);
    k_final<<<(B_ * 128) / 256, 256, 0, stream>>>(gen_part, comb_part, bgen, out, pflag);
}